// Round 7
// baseline (213.752 us; speedup 1.0000x reference)
//
#include <hip/hip_runtime.h>
#include <cstdint>
#include <cstddef>

// ---------------------------------------------------------------------------
// SparseMHADecoder: B=2, LQ=4096, LKV=2048, D=1024, H=16, d=64, span=16, stride=2
// R13: vectorize ctx_gather's compute+store (the last scalar-f16 kernel).
//      Old: per thread 512 scalar Vs reads + 64 scalar 2B global stores
//      (Common-mistake #2). New: thread owns (h, d8, q-parity); Vs read as
//      f16x8 (contiguous 1024B per wave, conflict-free), ctx written as f16x8
//      (fully coalesced). Accumulation order over i unchanged -> bit-identical.
//      Staging phase and ALL other kernels untouched (R12 = best-so-far).
// R12 carried: m97-structure pure-f16 GEMMs (qkv at structure ceiling,
//      <40us), f32->f16 convert hoisted into prep_all, workspace aliasing.
// R10 carried: coalesced staging, XCD A-panel grouping.
// R5/R6 carried: XOR chunk swizzle (0 bank conflicts all rounds).
// ---------------------------------------------------------------------------

typedef _Float16 f16;
typedef _Float16 f16x8 __attribute__((ext_vector_type(8)));
typedef float v4f __attribute__((ext_vector_type(4)));

#define B_  2
#define LQ_ 4096
#define LKV_ 2048
#define DMODEL 1024
#define NH 16
#define HD 64
#define SPAN 16
#define STRIDE 2

#define NQ_ELEMS  ((size_t)B_ * LQ_ * DMODEL)   // 8388608
#define NKV_ELEMS ((size_t)B_ * LKV_ * DMODEL)  // 4194304

__device__ __forceinline__ void async_copy16(const f16* g, f16* l) {
    __builtin_amdgcn_global_load_lds((const __attribute__((address_space(1))) void*)g,
                                     (__attribute__((address_space(3))) void*)l, 16, 0, 0);
}

// ---- prep: 4 weight transposes (blocks 0..1023) + q/k/v f32->f16 convert ----
__global__ __launch_bounds__(256)
void prep_all(const float* __restrict__ W0, const float* __restrict__ W1,
              const float* __restrict__ W2, const float* __restrict__ W3,
              f16* __restrict__ T0, f16* __restrict__ T1,
              f16* __restrict__ T2, f16* __restrict__ T3,
              const float* __restrict__ q, const float* __restrict__ k,
              const float* __restrict__ v,
              f16* __restrict__ qh, f16* __restrict__ kh, f16* __restrict__ vh) {
    const int t = threadIdx.x;
    const int bid = blockIdx.x;
    if (bid < 1024) {                       // 16x16 tiles x 4 weights
        const int z = bid >> 8, rem = bid & 255;
        const int bx = rem & 15, byy = rem >> 4;
        const float* W;
        f16* Wt;
        switch (z) {
            case 0: W = W0; Wt = T0; break;
            case 1: W = W1; Wt = T1; break;
            case 2: W = W2; Wt = T2; break;
            default: W = W3; Wt = T3; break;
        }
        __shared__ float tile[64][65];
        const int r0 = byy * 64, c0 = bx * 64;
        const int tx = t & 63, ty = t >> 6; // (64,4)
        for (int i = ty; i < 64; i += 4)
            tile[i][tx] = W[(long)(r0 + i) * DMODEL + c0 + tx];
        __syncthreads();
        for (int i = ty; i < 64; i += 4)
            Wt[(long)(c0 + i) * DMODEL + r0 + tx] = (f16)tile[tx][i];
    } else {                                // streaming f32 -> f16 convert
        const int cid = bid - 1024;         // 0..8191
        const float* src;
        f16* dst;
        size_t base;
        if (cid < 4096)      { src = q; dst = qh; base = (size_t)cid * 2048; }
        else if (cid < 6144) { src = k; dst = kh; base = (size_t)(cid - 4096) * 2048; }
        else                 { src = v; dst = vh; base = (size_t)(cid - 6144) * 2048; }
        const size_t i = base + (size_t)t * 8;
        const float4 lo = *(const float4*)(src + i);
        const float4 hi = *(const float4*)(src + i + 4);
        f16x8 o = {(f16)lo.x, (f16)lo.y, (f16)lo.z, (f16)lo.w,
                   (f16)hi.x, (f16)hi.y, (f16)hi.z, (f16)hi.w};
        *(f16x8*)(dst + i) = o;
    }
}

// ---------------- fp16 GEMM body, C[m][n] = sum_k A[m][k]*Bt[n][k] -----------
// 128x128 tile, BK=64, 256 thr = 4 waves, XOR chunk swizzle, BOTH operands
// via global_load_lds (pre-swizzled global src, linear LDS dest).
// Harness-verified m97 2-barrier structure (874-912 TF class on this chip).
template <bool OUT_F32>
__device__ __forceinline__ void gemm_body(const f16* __restrict__ Ah,
                                          const f16* __restrict__ Bt,
                                          void* __restrict__ Cv,
                                          int rowTile, int colTile) {
    constexpr int K = DMODEL, N = DMODEL;
    __shared__ f16 As[128 * 64];
    __shared__ f16 Bs[128 * 64];
    const int t = threadIdx.x;
    const int lane = t & 63;
    const int w = t >> 6;
    const int wm = w >> 1, wn = w & 1;
    const long rowBase = (long)rowTile * 128;
    const long colBase = (long)colTile * 128;
    const int qrow = lane & 15;
    const int quad = lane >> 4;

    v4f acc[4][4] = {};

    // staging: thread t covers rows srow+32i (i=0..3); LDS chunk schunk holds
    // global chunk schunk^(srow&7)  (8 f16 / 16B granularity)
    const int srow = t >> 3;          // 0..31
    const int schunk = t & 7;
    const int gchunk = schunk ^ (srow & 7);
    const f16* aptr = Ah + (rowBase + srow) * (long)K + gchunk * 8;
    const f16* bptr = Bt + (colBase + srow) * (long)K + gchunk * 8;
    f16* lA = &As[srow * 64 + schunk * 8];   // = t*8 : linear in t (DMA-legal)
    f16* lB = &Bs[srow * 64 + schunk * 8];

    for (int k0 = 0; k0 < K; k0 += 64) {
#pragma unroll
        for (int i = 0; i < 4; ++i)
            async_copy16(bptr + k0 + i * 32 * (long)K, lB + i * 2048);
#pragma unroll
        for (int i = 0; i < 4; ++i)
            async_copy16(aptr + k0 + i * 32 * (long)K, lA + i * 2048);
        __syncthreads();  // drains vmcnt+lgkm: staged tile visible
#pragma unroll
        for (int s = 0; s < 2; ++s) {   // two K=32 MFMA steps per BK=64 tile
            const int xk = (s * 4 + quad) ^ (qrow & 7);  // swizzled chunk
            f16x8 af[4], bf[4];
#pragma unroll
            for (int mt = 0; mt < 4; ++mt)
                af[mt] = *(const f16x8*)(&As[(wm * 64 + mt * 16 + qrow) * 64 + xk * 8]);
#pragma unroll
            for (int nt = 0; nt < 4; ++nt)
                bf[nt] = *(const f16x8*)(&Bs[(wn * 64 + nt * 16 + qrow) * 64 + xk * 8]);
#pragma unroll
            for (int mt = 0; mt < 4; ++mt)
#pragma unroll
                for (int nt = 0; nt < 4; ++nt)
                    acc[mt][nt] = __builtin_amdgcn_mfma_f32_16x16x32_f16(
                        af[mt], bf[nt], acc[mt][nt], 0, 0, 0);
        }
        __syncthreads();  // all reads done before next stage overwrites
    }

    // C/D layout (m89-verified): row = quad*4 + r, col = lane&15
#pragma unroll
    for (int mt = 0; mt < 4; ++mt)
#pragma unroll
        for (int nt = 0; nt < 4; ++nt) {
            const long col = colBase + wn * 64 + nt * 16 + qrow;
#pragma unroll
            for (int r = 0; r < 4; ++r) {
                const long row = rowBase + wm * 64 + mt * 16 + quad * 4 + r;
                if (OUT_F32)
                    ((float*)Cv)[row * (long)N + col] = acc[mt][nt][r];
                else
                    ((f16*)Cv)[row * (long)N + col] = (f16)acc[mt][nt][r];
            }
        }
}

// Fused Q/K/V projection from CONVERTED f16 inputs, 1024 blocks, XCD-swizzled.
__global__ __launch_bounds__(256, 2)
void gemm_qkv(const f16* __restrict__ A0, const f16* __restrict__ A1,
              const f16* __restrict__ A2, const f16* __restrict__ B0,
              const f16* __restrict__ B1, const f16* __restrict__ B2,
              f16* __restrict__ C0, f16* __restrict__ C1, f16* __restrict__ C2) {
    const int id = blockIdx.x;
    const int xcd = id & 7;
    const int g = id >> 3;            // 0..127
    const int ct = g & 7;             // col tile
    int rowIdx = (g >> 3) + xcd * 16; // 0..127
    const f16* A;
    const f16* Bt;
    f16* C;
    if (rowIdx < 64) {
        A = A0; Bt = B0; C = C0;
    } else if (rowIdx < 96) {
        A = A1; Bt = B1; C = C1; rowIdx -= 64;
    } else {
        A = A2; Bt = B2; C = C2; rowIdx -= 96;
    }
    gemm_body<false>(A, Bt, (void*)C, rowIdx, ct);
}

__global__ __launch_bounds__(256, 2)
void gemm_out(const f16* __restrict__ A, const f16* __restrict__ Bt,
              float* __restrict__ C) {
    const int id = blockIdx.x;        // 512 blocks
    const int xcd = id & 7;
    const int g = id >> 3;            // 0..63
    const int ct = g & 7;
    const int rowIdx = (g >> 3) + xcd * 8;  // 0..63
    gemm_body<true>(A, Bt, (void*)C, rowIdx, ct);
}

// -------- per-column scores + softmax over the 16 valid query rows ----------
__global__ __launch_bounds__(256)
void attn_scores(const f16* __restrict__ Q, const f16* __restrict__ Km,
                 float* __restrict__ attnw) {
    const int c0 = blockIdx.x * 4, b = blockIdx.y;
    const int t = threadIdx.x;
    __shared__ f16 Qs[24 * 1032];   // rows 0..21 used; 49.5 KB
    __shared__ f16 Ks[4 * 1032];    // 8.25 KB

#pragma unroll
    for (int it = 0; it < 12; ++it) {
        const int ch = t + 256 * it;        // 24 rows x 128 chunks
        const int row = ch >> 7, off = (ch & 127) * 8;
        int qq = 2 * c0 + row;
        if (qq > LQ_ - 1) qq = LQ_ - 1;     // clamp staging; masked in score
        f16x8 x = *(const f16x8*)(Q + (size_t)(b * LQ_ + qq) * DMODEL + off);
        const int h = off >> 6, bb = (off >> 3) & 7;
        *(f16x8*)(&Qs[row * 1032 + h * 64 + ((bb + h) & 7) * 8]) = x;
    }
#pragma unroll
    for (int it = 0; it < 2; ++it) {
        const int ch = t + 256 * it;        // 4 rows x 128 chunks
        const int row = ch >> 7, off = (ch & 127) * 8;
        f16x8 x = *(const f16x8*)(Km + (size_t)(b * LKV_ + c0 + row) * DMODEL + off);
        const int h = off >> 6, bb = (off >> 3) & 7;
        *(f16x8*)(&Ks[row * 1032 + h * 64 + ((bb + h) & 7) * 8]) = x;
    }
    __syncthreads();

    const int h = t >> 4, j = t & 15;
#pragma unroll
    for (int ci = 0; ci < 4; ++ci) {
        const int c = c0 + ci;
        const int q = STRIDE * c + j;
        const int row = 2 * ci + j;
        float a = 0.f;
#pragma unroll
        for (int bb = 0; bb < 8; ++bb) {
            const int off = h * 64 + ((bb + h) & 7) * 8;
            f16x8 qv = *(const f16x8*)(&Qs[row * 1032 + off]);
            f16x8 kv = *(const f16x8*)(&Ks[ci * 1032 + off]);  // wave-broadcast
#pragma unroll
            for (int u = 0; u < 8; ++u) a += (float)qv[u] * (float)kv[u];
        }
        float s = (q < LQ_) ? a : -1e30f;
        float m = s;
#pragma unroll
        for (int o = 1; o < 16; o <<= 1) m = fmaxf(m, __shfl_xor(m, o, 64));
        float p = (q < LQ_) ? __expf(s - m) : 0.f;
        float sum = p;
#pragma unroll
        for (int o = 1; o < 16; o <<= 1) sum += __shfl_xor(sum, o, 64);
        attnw[(size_t)((b * LKV_ + c) * NH + h) * SPAN + j] = p / sum;
    }
}

// ---- ctx[b,q,h,:] = sum_i attn[b, q/2-i, h, (q&1)+2i] * V[b, q/2-i, h, :] ----
// R13: staging unchanged; compute/store vectorized. Thread owns
// (h = (t&127)>>3, d8 = (t&7)*8, parity qh = t>>7) and produces 8 q-rows'
// f16x8 output chunks. Vs read f16x8 (wave-contiguous 1024B, conflict-free);
// ctx stored f16x8 (coalesced). i-ascending accumulation preserved.
__global__ __launch_bounds__(256)
void ctx_gather(const float* __restrict__ attnw, const f16* __restrict__ V,
                f16* __restrict__ ctx) {
    const int q0 = blockIdx.x * 16, b = blockIdx.y;
    const int t = threadIdx.x;
    const int kbase = (q0 >> 1) - 7;
    __shared__ f16 Vs[16 * 1024];     // 32 KB
    __shared__ float A_lds[16 * 256]; // 16 KB

#pragma unroll
    for (int it = 0; it < 8; ++it) {
        const int ch = t + 256 * it;       // 16 rows x 128 chunks
        const int row = ch >> 7, off = (ch & 127) * 8;
        int k = kbase + row;
        k = (k < 0) ? 0 : ((k > LKV_ - 1) ? LKV_ - 1 : k);
        *(f16x8*)(&Vs[row * 1024 + off]) =
            *(const f16x8*)(V + (size_t)(b * LKV_ + k) * DMODEL + off);
    }
#pragma unroll
    for (int it = 0; it < 4; ++it) {
        const int ch = t + 256 * it;       // 16 rows x 64 chunks of 4 f32
        const int row = ch >> 6, off = (ch & 63) * 4;
        int k = kbase + row;
        k = (k < 0) ? 0 : ((k > LKV_ - 1) ? LKV_ - 1 : k);
        *(float4*)(&A_lds[row * 256 + off]) =
            *(const float4*)(attnw + (size_t)(b * LKV_ + k) * 256 + off);
    }
    __syncthreads();

    const int chunk = t & 127;            // (h, d8)
    const int h = chunk >> 3;             // 0..15
    const int d8 = (chunk & 7) * 8;       // 0..56
    const int qh = t >> 7;                // q parity slot (q0 even)
    const int aoff = h * 16 + qh;
    const int kq0 = q0 >> 1;              // q>>1 for qp=0 (parity-free)

#pragma unroll
    for (int qp = 0; qp < 8; ++qp) {
        const int q = q0 + qp * 2 + qh;
        float acc[8] = {0.f, 0.f, 0.f, 0.f, 0.f, 0.f, 0.f, 0.f};
#pragma unroll
        for (int i = 0; i < 8; ++i) {
            if (kq0 + qp - i < 0) break;      // kq < 0 (first block only)
            const int rr = 7 + qp - i;        // kq - kbase, in [0,14]
            const float wgt = A_lds[rr * 256 + aoff + 2 * i];
            const f16x8 v8 = *(const f16x8*)(&Vs[rr * 1024 + h * 64 + d8]);
#pragma unroll
            for (int u = 0; u < 8; ++u) acc[u] += wgt * (float)v8[u];
        }
        f16x8 o = {(f16)acc[0], (f16)acc[1], (f16)acc[2], (f16)acc[3],
                   (f16)acc[4], (f16)acc[5], (f16)acc[6], (f16)acc[7]};
        *(f16x8*)(ctx + (size_t)(b * LQ_ + q) * DMODEL + h * HD + d8) = o;
    }
}

// ---------------------------------------------------------------------------
extern "C" void kernel_launch(void* const* d_in, const int* in_sizes, int n_in,
                              void* d_out, int out_size, void* d_ws, size_t ws_size,
                              hipStream_t stream) {
    const float* q  = (const float*)d_in[0];
    const float* k  = (const float*)d_in[1];
    const float* v  = (const float*)d_in[2];
    const float* Wq = (const float*)d_in[3];
    const float* Wk = (const float*)d_in[4];
    const float* Wv = (const float*)d_in[5];
    const float* Wo = (const float*)d_in[6];
    float* out = (float*)d_out;

    const size_t NW = (size_t)DMODEL * DMODEL;

    char* p = (char*)d_ws;
    f16* WqT = (f16*)p; p += NW * 2;                    // 2 MB
    f16* WkT = (f16*)p; p += NW * 2;
    f16* WvT = (f16*)p; p += NW * 2;
    f16* WoT = (f16*)p; p += NW * 2;
    f16* Qh  = (f16*)p; p += NQ_ELEMS * 2;              // 16 MB
    f16* Kh  = (f16*)p; p += NKV_ELEMS * 2;             // 8 MB
    f16* Vh  = (f16*)p; p += NKV_ELEMS * 2;             // 8 MB
    f16* qf  = (f16*)p; p += NQ_ELEMS * 2;              // 16 MB (dead after qkv)
    f16* kf  = (f16*)p; p += NKV_ELEMS * 2;             // 8 MB  (dead after qkv)
    f16* vf  = (f16*)p; p += NKV_ELEMS * 2;             // 8 MB  (dead after qkv)
    // aliases (lifetimes verified: qf/kf dead once gemm_qkv completes)
    f16* ctxh = qf;                                     // 16 MB needed
    float* attnw = (float*)kf;                          // 4 MB needed <= 8 MB

    // 1) weight transposes + q/k/v f32->f16 convert (one fused launch)
    prep_all<<<dim3(9216), 256, 0, stream>>>(Wq, Wk, Wv, Wo, WqT, WkT, WvT, WoT,
                                             q, k, v, qf, kf, vf);

    // 2) Q/K/V projections, pure-f16 m97 structure, XCD-swizzled
    gemm_qkv<<<dim3(1024), 256, 0, stream>>>(qf, kf, vf, WqT, WkT, WvT,
                                             Qh, Kh, Vh);

    // 3) per-column masked scores + query-axis softmax
    attn_scores<<<dim3(LKV_ / 4, B_), 256, 0, stream>>>(Qh, Kh, attnw);

    // 4) per-query gather of weighted V (vectorized)
    ctx_gather<<<dim3(LQ_ / 16, B_), 256, 0, stream>>>(attnw, Vh, ctxh);

    // 5) output projection (f32 out), XCD-swizzled
    gemm_out<<<dim3(512), 256, 0, stream>>>(ctxh, WoT, out);
}

// Round 9
// 209.102 us; speedup vs baseline: 1.0222x; 1.0222x over previous
//
#include <hip/hip_runtime.h>
#include <cstdint>
#include <cstddef>

// ---------------------------------------------------------------------------
// SparseMHADecoder: B=2, LQ=4096, LKV=2048, D=1024, H=16, d=64, span=16, stride=2
// R15: fix R14's correctness bug (absmax 0.92). Root cause: phase "halves"
//      (per-wave accumulator quadrants) did not coincide with STAGING halves
//      (rows 0-127 / 128-255): wave wm=1 read Ahi at P1, waves wn>=2 read Bhi
//      at P1 -> unstaged LDS. Fix: wave tile = two 64-row strips, one per
//      staging half:  A-row = h*128 + wm*64 + m4*16 + qrow,
//                     B-col = h*128 + wn*32 + n2*16 + qrow.
//      Now DSA/DSB(h) touch ONLY staging half h for every wave; each phase's
//      reads are covered by the preceding counted-vmcnt+barrier (ledger
//      re-verified per half, prologue + 16 iters + tail). Epilogue remapped
//      to match. Per-element k-order unchanged -> absmax 0.015625 expected.
// R14 carried: quadrant-phased 256x256 gemm_qkv, 4 phases/K-tile, deadline-
//      ordered staging (Alo@P1,Blo@P2,Bhi@P3,Ahi@P4), counted vmcnt(4) (T4),
//      setprio on MFMA (T5), gload_lds-only staging.
// R13 carried: vectorized ctx_gather. R12: prep_all hoisted convert, m97
//      gemm_out, workspace aliasing. R5/R6/R10: XOR swizzle, coalescing, XCD.
// ---------------------------------------------------------------------------

typedef _Float16 f16;
typedef _Float16 f16x8 __attribute__((ext_vector_type(8)));
typedef float v4f __attribute__((ext_vector_type(4)));

#define B_  2
#define LQ_ 4096
#define LKV_ 2048
#define DMODEL 1024
#define NH 16
#define HD 64
#define SPAN 16
#define STRIDE 2

#define NQ_ELEMS  ((size_t)B_ * LQ_ * DMODEL)   // 8388608
#define NKV_ELEMS ((size_t)B_ * LKV_ * DMODEL)  // 4194304

#define BAR()   __builtin_amdgcn_s_barrier()
#define LGKM0() asm volatile("s_waitcnt lgkmcnt(0)" ::: "memory")
#define SB0()   __builtin_amdgcn_sched_barrier(0)
#define VM4()   asm volatile("s_waitcnt vmcnt(4)" ::: "memory")
#define VM2()   asm volatile("s_waitcnt vmcnt(2)" ::: "memory")
#define VM0()   asm volatile("s_waitcnt vmcnt(0)" ::: "memory")

__device__ __forceinline__ void async_copy16(const f16* g, f16* l) {
    __builtin_amdgcn_global_load_lds((const __attribute__((address_space(1))) void*)g,
                                     (__attribute__((address_space(3))) void*)l, 16, 0, 0);
}

// ---- prep: 4 weight transposes (blocks 0..1023) + q/k/v f32->f16 convert ----
__global__ __launch_bounds__(256)
void prep_all(const float* __restrict__ W0, const float* __restrict__ W1,
              const float* __restrict__ W2, const float* __restrict__ W3,
              f16* __restrict__ T0, f16* __restrict__ T1,
              f16* __restrict__ T2, f16* __restrict__ T3,
              const float* __restrict__ q, const float* __restrict__ k,
              const float* __restrict__ v,
              f16* __restrict__ qh, f16* __restrict__ kh, f16* __restrict__ vh) {
    const int t = threadIdx.x;
    const int bid = blockIdx.x;
    if (bid < 1024) {                       // 16x16 tiles x 4 weights
        const int z = bid >> 8, rem = bid & 255;
        const int bx = rem & 15, byy = rem >> 4;
        const float* W;
        f16* Wt;
        switch (z) {
            case 0: W = W0; Wt = T0; break;
            case 1: W = W1; Wt = T1; break;
            case 2: W = W2; Wt = T2; break;
            default: W = W3; Wt = T3; break;
        }
        __shared__ float tile[64][65];
        const int r0 = byy * 64, c0 = bx * 64;
        const int tx = t & 63, ty = t >> 6; // (64,4)
        for (int i = ty; i < 64; i += 4)
            tile[i][tx] = W[(long)(r0 + i) * DMODEL + c0 + tx];
        __syncthreads();
        for (int i = ty; i < 64; i += 4)
            Wt[(long)(c0 + i) * DMODEL + r0 + tx] = (f16)tile[tx][i];
    } else {                                // streaming f32 -> f16 convert
        const int cid = bid - 1024;         // 0..8191
        const float* src;
        f16* dst;
        size_t base;
        if (cid < 4096)      { src = q; dst = qh; base = (size_t)cid * 2048; }
        else if (cid < 6144) { src = k; dst = kh; base = (size_t)(cid - 4096) * 2048; }
        else                 { src = v; dst = vh; base = (size_t)(cid - 6144) * 2048; }
        const size_t i = base + (size_t)t * 8;
        const float4 lo = *(const float4*)(src + i);
        const float4 hi = *(const float4*)(src + i + 4);
        f16x8 o = {(f16)lo.x, (f16)lo.y, (f16)lo.z, (f16)lo.w,
                   (f16)hi.x, (f16)hi.y, (f16)hi.z, (f16)hi.w};
        *(f16x8*)(dst + i) = o;
    }
}

// ---------------------------------------------------------------------------
// R15 quadrant-phased 256x256 GEMM body (f16 x f16 -> f16).
// K-tile t in buf[t&1] (A 16384 f16 then B 16384 f16, 64KB).
// Staging halves: half h = block rows h*128..h*128+127 (A) / cols (B).
// Wave tile: A strips {h*128 + wm*64 .. +63}, B strips {h*128 + wn*32 .. +31}.
// ---------------------------------------------------------------------------
__device__ __forceinline__ void gemm_qkv_body(const f16* __restrict__ Ah,
                                              const f16* __restrict__ Bt,
                                              f16* __restrict__ C,
                                              int rowTile, int colTile) {
    constexpr int K = DMODEL, N = DMODEL, NT = K / 64;
    __shared__ f16 lds[2 * 32768];          // 128 KB

    const int t = threadIdx.x;              // 512
    const int lane = t & 63, w = t >> 6;
    const int wm = w >> 2, wn = w & 3;      // 2M x 4N
    const int qrow = lane & 15, quad = lane >> 4;
    const long rowBase = (long)rowTile * 256;
    const long colBase = (long)colTile * 256;

    // staging geometry: thread covers chunk (t&7) of rows (t>>3) + 64j,
    // swizzled on the GLOBAL side, linear LDS dest (= t*8 + j*4096).
    const int srow = t >> 3, sch = t & 7;
    const int gch = sch ^ (srow & 7);       // thread-constant
    const f16* aBase = Ah + (rowBase + srow) * (long)K + gch * 8;
    const f16* bBase = Bt + (colBase + srow) * (long)K + gch * 8;

    v4f acc[8][4] = {};
    f16x8 afr[4][2];                        // current A-half frags [m4][s]
    f16x8 bfr[4][2];                        // both B-halves kept  [bh*2+n2][s]

    auto STAGE = [&](int tt2, int op, int half) {   // 1 op-half = 2 gloads
        f16* dst = &lds[(tt2 & 1) * 32768 + op * 16384 + half * 8192 + t * 8];
        const f16* src = (op ? bBase : aBase) + (long)half * 128 * K + tt2 * 64;
        async_copy16(src, dst);
        async_copy16(src + 64 * (long)K, dst + 4096);
    };
    auto DSA = [&](int tt2, int h) {        // 8 ds_read_b128, half h ONLY
        const f16* lp = &lds[(tt2 & 1) * 32768];
#pragma unroll
        for (int m4 = 0; m4 < 4; ++m4)
#pragma unroll
            for (int s = 0; s < 2; ++s)
                afr[m4][s] = *(const f16x8*)(lp +
                    (h * 128 + wm * 64 + m4 * 16 + qrow) * 64 +
                    (((s * 4 + quad) ^ (qrow & 7)) * 8));
    };
    auto DSB = [&](int tt2, int h) {        // 4 ds_read_b128, half h ONLY
        const f16* lp = &lds[(tt2 & 1) * 32768 + 16384];
#pragma unroll
        for (int n2 = 0; n2 < 2; ++n2)
#pragma unroll
            for (int s = 0; s < 2; ++s)
                bfr[h * 2 + n2][s] = *(const f16x8*)(lp +
                    (h * 128 + wn * 32 + n2 * 16 + qrow) * 64 +
                    (((s * 4 + quad) ^ (qrow & 7)) * 8));
    };
    auto MQ = [&](int ah, int bh) {         // 16 MFMA, one C-quadrant
        __builtin_amdgcn_s_setprio(1);
#pragma unroll
        for (int s = 0; s < 2; ++s)
#pragma unroll
            for (int m4 = 0; m4 < 4; ++m4)
#pragma unroll
                for (int n2 = 0; n2 < 2; ++n2)
                    acc[ah * 4 + m4][bh * 2 + n2] =
                        __builtin_amdgcn_mfma_f32_16x16x32_f16(
                            afr[m4][s], bfr[bh * 2 + n2][s],
                            acc[ah * 4 + m4][bh * 2 + n2], 0, 0, 0);
        __builtin_amdgcn_s_setprio(0);
    };

    // ---- prologue: tile0 fully staged ----
    STAGE(0, 0, 0); STAGE(0, 1, 0); STAGE(0, 1, 1); STAGE(0, 0, 1);
    VM0();
    BAR();

    // ---- main loop: 4 phases per K-tile ----
#pragma unroll 2
    for (int tt = 0; tt < NT; ++tt) {
        const bool st = (tt + 1 < NT);
        // P1: Q(lo,lo)  reads A half0 + B half0 of t; stages Alo of t+1
        DSA(tt, 0); DSB(tt, 0);
        if (st) STAGE(tt + 1, 0, 0);
        BAR(); LGKM0(); SB0();
        MQ(0, 0);
        if (st) { VM4(); } else { VM2(); }   // -> Bhi(t) retired for P2
        BAR();
        // P2: Q(lo,hi)  reads B half1 of t; stages Blo of t+1
        DSB(tt, 1);
        if (st) STAGE(tt + 1, 1, 0);
        BAR(); LGKM0(); SB0();
        MQ(0, 1);
        if (st) { VM4(); } else { VM0(); }   // -> Ahi(t) retired for P3
        BAR();
        // P3: Q(hi,lo)  reads A half1 of t; stages Bhi of t+1
        DSA(tt, 1);
        if (st) STAGE(tt + 1, 1, 1);
        BAR(); LGKM0(); SB0();
        MQ(1, 0);
        BAR();
        // P4: Q(hi,hi)  all frags in regs; stages Ahi of t+1
        if (st) STAGE(tt + 1, 0, 1);
        MQ(1, 1);
        if (st) VM4();                       // -> Alo+Blo(t+1) retired for next P1
        BAR();
    }

    // ---- epilogue: C/D layout (m89-verified): row = quad*4 + r, col = qrow.
    // Wave-tile mapping matches DSA/DSB strips.
#pragma unroll
    for (int m = 0; m < 8; ++m)
#pragma unroll
        for (int n = 0; n < 4; ++n) {
            const int ah = m >> 2, m4 = m & 3;
            const int bh = n >> 1, n2 = n & 1;
            const long col = colBase + bh * 128 + wn * 32 + n2 * 16 + qrow;
#pragma unroll
            for (int r = 0; r < 4; ++r) {
                const long row = rowBase + ah * 128 + wm * 64 + m4 * 16 + quad * 4 + r;
                C[row * (long)N + col] = (f16)acc[m][n][r];
            }
        }
}

// 256 blocks (Q: 32rt x 4ct, K: 16x4, V: 16x4) x 512 thr = 1 block/CU.
__global__ __launch_bounds__(512)
void gemm_qkv(const f16* __restrict__ qf, const f16* __restrict__ kf,
              const f16* __restrict__ vf, const f16* __restrict__ WqT,
              const f16* __restrict__ WkT, const f16* __restrict__ WvT,
              f16* __restrict__ Qh, f16* __restrict__ Kh, f16* __restrict__ Vh) {
    const int id = (blockIdx.x & 7) * 32 + (blockIdx.x >> 3);  // bijective, 256
    const f16* A; const f16* Bt; f16* C; int rt, ct;
    if (id < 128)      { A = qf; Bt = WqT; C = Qh; rt = id >> 2; ct = id & 3; }
    else if (id < 192) { const int g = id - 128; A = kf; Bt = WkT; C = Kh; rt = g >> 2; ct = g & 3; }
    else               { const int g = id - 192; A = vf; Bt = WvT; C = Vh; rt = g >> 2; ct = g & 3; }
    gemm_qkv_body(A, Bt, C, rt, ct);
}

// ---------------- fp16 GEMM body (m97 2-barrier, R12-verified) --------------
template <bool OUT_F32>
__device__ __forceinline__ void gemm_body(const f16* __restrict__ Ah,
                                          const f16* __restrict__ Bt,
                                          void* __restrict__ Cv,
                                          int rowTile, int colTile) {
    constexpr int K = DMODEL, N = DMODEL;
    __shared__ f16 As[128 * 64];
    __shared__ f16 Bs[128 * 64];
    const int t = threadIdx.x;
    const int lane = t & 63;
    const int w = t >> 6;
    const int wm = w >> 1, wn = w & 1;
    const long rowBase = (long)rowTile * 128;
    const long colBase = (long)colTile * 128;
    const int qrow = lane & 15;
    const int quad = lane >> 4;

    v4f acc[4][4] = {};

    const int srow = t >> 3;          // 0..31
    const int schunk = t & 7;
    const int gchunk = schunk ^ (srow & 7);
    const f16* aptr = Ah + (rowBase + srow) * (long)K + gchunk * 8;
    const f16* bptr = Bt + (colBase + srow) * (long)K + gchunk * 8;
    f16* lA = &As[srow * 64 + schunk * 8];
    f16* lB = &Bs[srow * 64 + schunk * 8];

    for (int k0 = 0; k0 < K; k0 += 64) {
#pragma unroll
        for (int i = 0; i < 4; ++i)
            async_copy16(bptr + k0 + i * 32 * (long)K, lB + i * 2048);
#pragma unroll
        for (int i = 0; i < 4; ++i)
            async_copy16(aptr + k0 + i * 32 * (long)K, lA + i * 2048);
        __syncthreads();
#pragma unroll
        for (int s = 0; s < 2; ++s) {
            const int xk = (s * 4 + quad) ^ (qrow & 7);
            f16x8 af[4], bf[4];
#pragma unroll
            for (int mt = 0; mt < 4; ++mt)
                af[mt] = *(const f16x8*)(&As[(wm * 64 + mt * 16 + qrow) * 64 + xk * 8]);
#pragma unroll
            for (int nt = 0; nt < 4; ++nt)
                bf[nt] = *(const f16x8*)(&Bs[(wn * 64 + nt * 16 + qrow) * 64 + xk * 8]);
#pragma unroll
            for (int mt = 0; mt < 4; ++mt)
#pragma unroll
                for (int nt = 0; nt < 4; ++nt)
                    acc[mt][nt] = __builtin_amdgcn_mfma_f32_16x16x32_f16(
                        af[mt], bf[nt], acc[mt][nt], 0, 0, 0);
        }
        __syncthreads();
    }

#pragma unroll
    for (int mt = 0; mt < 4; ++mt)
#pragma unroll
        for (int nt = 0; nt < 4; ++nt) {
            const long col = colBase + wn * 64 + nt * 16 + qrow;
#pragma unroll
            for (int r = 0; r < 4; ++r) {
                const long row = rowBase + wm * 64 + mt * 16 + quad * 4 + r;
                if (OUT_F32)
                    ((float*)Cv)[row * (long)N + col] = acc[mt][nt][r];
                else
                    ((f16*)Cv)[row * (long)N + col] = (f16)acc[mt][nt][r];
            }
        }
}

__global__ __launch_bounds__(256, 2)
void gemm_out(const f16* __restrict__ A, const f16* __restrict__ Bt,
              float* __restrict__ C) {
    const int id = blockIdx.x;        // 512 blocks
    const int xcd = id & 7;
    const int g = id >> 3;            // 0..63
    const int ct = g & 7;
    const int rowIdx = (g >> 3) + xcd * 8;  // 0..63
    gemm_body<true>(A, Bt, (void*)C, rowIdx, ct);
}

// -------- per-column scores + softmax over the 16 valid query rows ----------
__global__ __launch_bounds__(256)
void attn_scores(const f16* __restrict__ Q, const f16* __restrict__ Km,
                 float* __restrict__ attnw) {
    const int c0 = blockIdx.x * 4, b = blockIdx.y;
    const int t = threadIdx.x;
    __shared__ f16 Qs[24 * 1032];   // rows 0..21 used; 49.5 KB
    __shared__ f16 Ks[4 * 1032];    // 8.25 KB

#pragma unroll
    for (int it = 0; it < 12; ++it) {
        const int ch = t + 256 * it;        // 24 rows x 128 chunks
        const int row = ch >> 7, off = (ch & 127) * 8;
        int qq = 2 * c0 + row;
        if (qq > LQ_ - 1) qq = LQ_ - 1;     // clamp staging; masked in score
        f16x8 x = *(const f16x8*)(Q + (size_t)(b * LQ_ + qq) * DMODEL + off);
        const int h = off >> 6, bb = (off >> 3) & 7;
        *(f16x8*)(&Qs[row * 1032 + h * 64 + ((bb + h) & 7) * 8]) = x;
    }
#pragma unroll
    for (int it = 0; it < 2; ++it) {
        const int ch = t + 256 * it;        // 4 rows x 128 chunks
        const int row = ch >> 7, off = (ch & 127) * 8;
        f16x8 x = *(const f16x8*)(Km + (size_t)(b * LKV_ + c0 + row) * DMODEL + off);
        const int h = off >> 6, bb = (off >> 3) & 7;
        *(f16x8*)(&Ks[row * 1032 + h * 64 + ((bb + h) & 7) * 8]) = x;
    }
    __syncthreads();

    const int h = t >> 4, j = t & 15;
#pragma unroll
    for (int ci = 0; ci < 4; ++ci) {
        const int c = c0 + ci;
        const int q = STRIDE * c + j;
        const int row = 2 * ci + j;
        float a = 0.f;
#pragma unroll
        for (int bb = 0; bb < 8; ++bb) {
            const int off = h * 64 + ((bb + h) & 7) * 8;
            f16x8 qv = *(const f16x8*)(&Qs[row * 1032 + off]);
            f16x8 kv = *(const f16x8*)(&Ks[ci * 1032 + off]);  // wave-broadcast
#pragma unroll
            for (int u = 0; u < 8; ++u) a += (float)qv[u] * (float)kv[u];
        }
        float s = (q < LQ_) ? a : -1e30f;
        float m = s;
#pragma unroll
        for (int o = 1; o < 16; o <<= 1) m = fmaxf(m, __shfl_xor(m, o, 64));
        float p = (q < LQ_) ? __expf(s - m) : 0.f;
        float sum = p;
#pragma unroll
        for (int o = 1; o < 16; o <<= 1) sum += __shfl_xor(sum, o, 64);
        attnw[(size_t)((b * LKV_ + c) * NH + h) * SPAN + j] = p / sum;
    }
}

// ---- ctx[b,q,h,:] = sum_i attn[b, q/2-i, h, (q&1)+2i] * V[b, q/2-i, h, :] ----
__global__ __launch_bounds__(256)
void ctx_gather(const float* __restrict__ attnw, const f16* __restrict__ V,
                f16* __restrict__ ctx) {
    const int q0 = blockIdx.x * 16, b = blockIdx.y;
    const int t = threadIdx.x;
    const int kbase = (q0 >> 1) - 7;
    __shared__ f16 Vs[16 * 1024];     // 32 KB
    __shared__ float A_lds[16 * 256]; // 16 KB

#pragma unroll
    for (int it = 0; it < 8; ++it) {
        const int ch = t + 256 * it;       // 16 rows x 128 chunks
        const int row = ch >> 7, off = (ch & 127) * 8;
        int k = kbase + row;
        k = (k < 0) ? 0 : ((k > LKV_ - 1) ? LKV_ - 1 : k);
        *(f16x8*)(&Vs[row * 1024 + off]) =
            *(const f16x8*)(V + (size_t)(b * LKV_ + k) * DMODEL + off);
    }
#pragma unroll
    for (int it = 0; it < 4; ++it) {
        const int ch = t + 256 * it;       // 16 rows x 64 chunks of 4 f32
        const int row = ch >> 6, off = (ch & 63) * 4;
        int k = kbase + row;
        k = (k < 0) ? 0 : ((k > LKV_ - 1) ? LKV_ - 1 : k);
        *(float4*)(&A_lds[row * 256 + off]) =
            *(const float4*)(attnw + (size_t)(b * LKV_ + k) * 256 + off);
    }
    __syncthreads();

    const int chunk = t & 127;            // (h, d8)
    const int h = chunk >> 3;             // 0..15
    const int d8 = (chunk & 7) * 8;       // 0..56
    const int qh = t >> 7;                // q parity slot (q0 even)
    const int aoff = h * 16 + qh;
    const int kq0 = q0 >> 1;

#pragma unroll
    for (int qp = 0; qp < 8; ++qp) {
        const int q = q0 + qp * 2 + qh;
        float acc[8] = {0.f, 0.f, 0.f, 0.f, 0.f, 0.f, 0.f, 0.f};
#pragma unroll
        for (int i = 0; i < 8; ++i) {
            if (kq0 + qp - i < 0) break;      // kq < 0 (first block only)
            const int rr = 7 + qp - i;        // kq - kbase, in [0,14]
            const float wgt = A_lds[rr * 256 + aoff + 2 * i];
            const f16x8 v8 = *(const f16x8*)(&Vs[rr * 1024 + h * 64 + d8]);
#pragma unroll
            for (int u = 0; u < 8; ++u) acc[u] += wgt * (float)v8[u];
        }
        f16x8 o = {(f16)acc[0], (f16)acc[1], (f16)acc[2], (f16)acc[3],
                   (f16)acc[4], (f16)acc[5], (f16)acc[6], (f16)acc[7]};
        *(f16x8*)(ctx + (size_t)(b * LQ_ + q) * DMODEL + h * HD + d8) = o;
    }
}

// ---------------------------------------------------------------------------
extern "C" void kernel_launch(void* const* d_in, const int* in_sizes, int n_in,
                              void* d_out, int out_size, void* d_ws, size_t ws_size,
                              hipStream_t stream) {
    const float* q  = (const float*)d_in[0];
    const float* k  = (const float*)d_in[1];
    const float* v  = (const float*)d_in[2];
    const float* Wq = (const float*)d_in[3];
    const float* Wk = (const float*)d_in[4];
    const float* Wv = (const float*)d_in[5];
    const float* Wo = (const float*)d_in[6];
    float* out = (float*)d_out;

    const size_t NW = (size_t)DMODEL * DMODEL;

    char* p = (char*)d_ws;
    f16* WqT = (f16*)p; p += NW * 2;                    // 2 MB
    f16* WkT = (f16*)p; p += NW * 2;
    f16* WvT = (f16*)p; p += NW * 2;
    f16* WoT = (f16*)p; p += NW * 2;
    f16* Qh  = (f16*)p; p += NQ_ELEMS * 2;              // 16 MB
    f16* Kh  = (f16*)p; p += NKV_ELEMS * 2;             // 8 MB
    f16* Vh  = (f16*)p; p += NKV_ELEMS * 2;             // 8 MB
    f16* qf  = (f16*)p; p += NQ_ELEMS * 2;              // 16 MB (dead after qkv)
    f16* kf  = (f16*)p; p += NKV_ELEMS * 2;             // 8 MB  (dead after qkv)
    f16* vf  = (f16*)p; p += NKV_ELEMS * 2;             // 8 MB  (dead after qkv)
    f16* ctxh = qf;                                     // alias (lifetime ok)
    float* attnw = (float*)kf;                          // alias (lifetime ok)

    // 1) weight transposes + q/k/v f32->f16 convert (one fused launch)
    prep_all<<<dim3(9216), 256, 0, stream>>>(Wq, Wk, Wv, Wo, WqT, WkT, WvT, WoT,
                                             q, k, v, qf, kf, vf);

    // 2) Q/K/V projections, quadrant-phased 256x256, 1 block/CU
    gemm_qkv<<<dim3(256), 512, 0, stream>>>(qf, kf, vf, WqT, WkT, WvT,
                                            Qh, Kh, Vh);

    // 3) per-column masked scores + query-axis softmax
    attn_scores<<<dim3(LKV_ / 4, B_), 256, 0, stream>>>(Qh, Kh, attnw);

    // 4) per-query gather of weighted V (vectorized)
    ctx_gather<<<dim3(LQ_ / 16, B_), 256, 0, stream>>>(attnw, Vh, ctxh);

    // 5) output projection (f32 out), m97 structure, XCD-swizzled
    gemm_out<<<dim3(512), 256, 0, stream>>>(ctxh, WoT, out);
}